// Round 12
// baseline (503.115 us; speedup 1.0000x reference)
//
#include <hip/hip_runtime.h>

#define DEVI __device__ __forceinline__

typedef short v8s __attribute__((ext_vector_type(8)));
typedef float v4f __attribute__((ext_vector_type(4)));
typedef unsigned short u16;

typedef __attribute__((address_space(3))) unsigned int lds_u32;
typedef const __attribute__((address_space(1))) unsigned int glb_u32;

DEVI float bf2f(short s) {
  union { unsigned u; float f; } cv;
  cv.u = ((unsigned)(u16)s) << 16;
  return cv.f;
}
DEVI short f2bf(float f) {
  union { float f; unsigned u; } cv; cv.f = f;
  unsigned u = cv.u;
  return (short)((u + 0x7FFFu + ((u >> 16) & 1u)) >> 16);
}
DEVI void gld16(const void* g, void* l) {
  __builtin_amdgcn_global_load_lds((glb_u32*)g, (lds_u32*)l, 16, 0, 0);
}
#define SBAR() __builtin_amdgcn_s_barrier()
#define SCHED0() __builtin_amdgcn_sched_barrier(0)

// ---------------- prep: transpose + cast weights to bf16 ----------------
__global__ void prep_weights(const float* __restrict__ Wq, const float* __restrict__ Wk,
                             const float* __restrict__ Wv, const float* __restrict__ Wout,
                             short* __restrict__ WcT, short* __restrict__ WoT) {
  int n = blockIdx.x;
  int k = threadIdx.x;
  float v;
  if (n < 256)      v = Wq[k * 256 + n];
  else if (n < 512) v = Wk[k * 256 + (n - 256)];
  else              v = Wv[k * 256 + (n - 512)];
  WcT[n * 256 + k] = f2bf(v);
  if (n < 256) WoT[n * 256 + k] = f2bf(Wout[k * 256 + n]);
}

// ---------------- x -> bf16 cast ----------------
__global__ void x_cast(const float* __restrict__ x, short* __restrict__ xb) {
  for (size_t gidx = (size_t)blockIdx.x * 256 + threadIdx.x; gidx < 4194304;
       gidx += (size_t)4096 * 256) {
    const float4* src = reinterpret_cast<const float4*>(x + gidx * 8);
    float4 a = src[0], c = src[1];
    v8s pk;
    pk[0] = f2bf(a.x); pk[1] = f2bf(a.y); pk[2] = f2bf(a.z); pk[3] = f2bf(a.w);
    pk[4] = f2bf(c.x); pk[5] = f2bf(c.y); pk[6] = f2bf(c.z); pk[7] = f2bf(c.w);
    *reinterpret_cast<v8s*>(xb + gidx * 8) = pk;
  }
}

// ---------------- QKV projection: B-resident (R8 tile layout) + A dbuf, 1 barrier/step ----------------
// LDS: B 4x16KB (staged once) + A 2x16KB dbuf = 96 KB; 1 block/CU; grid 1536 XCD-chunked.
// Per step: vmcnt(aged stage) + 1 barrier + 4 gld16 + 16 MFMA/wave. No mid-loop drain.
__launch_bounds__(256, 1)
__global__ void proj_gemm(const short* __restrict__ xb, const short* __restrict__ WcT,
                          const float* __restrict__ pos_emb,
                          short* __restrict__ Qb, short* __restrict__ Kb,
                          short* __restrict__ Vb) {
  __shared__ short Bs[4][128 * 64];    // B tile per ks, R8 layout (128B rows, XOR swizzle)
  __shared__ short Aa[2][128 * 64];    // A dbuf
  const int t = threadIdx.x;
  const int bi = blockIdx.x;
  const int xcd = bi & 7;
  const int j = bi >> 3;               // 0..191
  const int mgl = j / 6, nt = j % 6;
  const int mtg = xcd * 32 + mgl;      // 0..255, bijective
  const int m0 = mtg * 512;            // 4 m-tiles of 128 rows
  const int n0 = nt * 128;
  const int wave = t >> 6, lane = t & 63;
  const int wm = (wave & 1) * 64, wn = (wave >> 1) * 64;
  const int lr = lane & 15, g = lane >> 4;

  // DMA source (pre-swizzled, R8 involution): lane -> row-in-8 = ro, col bytes ^ (ro<<4)
  const int ro = lane >> 3;
  const int colb = ((lane & 7) * 16) ^ (ro << 4);
  const char* aSrc0 = reinterpret_cast<const char*>(xb + (size_t)(m0 + ro) * 256) + colb;
  const char* bSrc0 = reinterpret_cast<const char*>(WcT + (size_t)(n0 + ro) * 256) + colb;

  // prologue: stage ALL of B (4 tiles) + A step 0
#pragma unroll
  for (int ks = 0; ks < 4; ++ks) {
#pragma unroll
    for (int c = 0; c < 4; ++c) {
      int cc = wave * 4 + c;
      gld16(bSrc0 + (size_t)cc * 8 * 512 + ks * 128, (char*)Bs[ks] + cc * 1024);
    }
  }
#pragma unroll
  for (int c = 0; c < 4; ++c) {
    int cc = wave * 4 + c;
    gld16(aSrc0 + (size_t)cc * 8 * 512, (char*)Aa[0] + cc * 1024);
  }

  v4f acc[4][4];
#pragma unroll
  for (int i = 0; i < 4; ++i)
#pragma unroll
    for (int jj = 0; jj < 4; ++jj) acc[i][jj] = (v4f){0.f, 0.f, 0.f, 0.f};

#pragma unroll 1
  for (int s = 0; s < 16; ++s) {
    const int buf = s & 1;
    // wait for stage(s) (and, every 4th step, the prior epilogue stores) -- all aged ~1 step
    asm volatile("s_waitcnt vmcnt(0)" ::: "memory");
    SBAR();              // all waves' DMAs landed; step s-1 fully done (buf^1 free)
    SCHED0();

    if (s < 15) {        // stage A(s+1) into buf^1 (safe: freed by the barrier above)
      const int sn = s + 1;
      const char* aS = aSrc0 + (size_t)(sn >> 2) * 128 * 512 + (sn & 3) * 128;
#pragma unroll
      for (int c = 0; c < 4; ++c) {
        int cc = wave * 4 + c;
        gld16(aS + (size_t)cc * 8 * 512, (char*)Aa[buf ^ 1] + cc * 1024);
      }
    }

    const char* aB = (const char*)Aa[buf];
    const char* bB = (const char*)Bs[s & 3];
#pragma unroll
    for (int kk = 0; kk < 2; ++kk) {
      v8s af[4], bfr[4];
#pragma unroll
      for (int i = 0; i < 4; ++i) {
        int row = wm + i * 16 + lr;
        int byte = (row * 128 + kk * 64 + g * 16) ^ ((row & 7) << 4);
        af[i] = *reinterpret_cast<const v8s*>(aB + byte);
      }
#pragma unroll
      for (int jj = 0; jj < 4; ++jj) {
        int rn = wn + jj * 16 + lr;
        int byte = (rn * 128 + kk * 64 + g * 16) ^ ((rn & 7) << 4);
        bfr[jj] = *reinterpret_cast<const v8s*>(bB + byte);
      }
#pragma unroll
      for (int i = 0; i < 4; ++i)
#pragma unroll
        for (int jj = 0; jj < 4; ++jj)
          acc[i][jj] = __builtin_amdgcn_mfma_f32_16x16x32_bf16(af[i], bfr[jj], acc[i][jj], 0, 0, 0);
    }

    if ((s & 3) == 3) {
      // epilogue for m-tile u (register-only + global stores; no LDS access)
      const int u = s >> 2;
#pragma unroll
      for (int i = 0; i < 4; ++i) {
#pragma unroll
        for (int jj = 0; jj < 4; ++jj) {
          int colg = n0 + wn + jj * 16 + lr;
#pragma unroll
          for (int r = 0; r < 4; ++r) {
            int p = m0 + u * 128 + wm + i * 16 + g * 4 + r;
            float v = acc[i][jj][r];
            if (nt < 2) {
              int yy = (p >> 7) & 127, xx = p & 127;
              int qi = (yy - min(max(yy, 2), 125) + 2) * 5 + (xx - min(max(xx, 2), 125) + 2);
              v += pos_emb[qi * 256 + colg];
              Qb[(size_t)p * 256 + colg] = f2bf(v);
            } else if (nt < 4) {
              Kb[(size_t)p * 256 + (colg - 256)] = f2bf(v);
            } else {
              Vb[(size_t)p * 256 + (colg - 512)] = f2bf(v);
            }
            acc[i][jj][r] = 0.f;
          }
        }
      }
    }
  }
}

// ---------------- attention: split-F + depth-1 K/V register prefetch ----------------
__launch_bounds__(256, 4)
__global__ void attn_kernel(const short* __restrict__ Qb, const short* __restrict__ Kb,
                            const short* __restrict__ Vb, const float* __restrict__ pos_emb,
                            short* __restrict__ ACC) {
  __shared__ float pe[25 * 256];
  for (int i = threadIdx.x; i < 1600; i += 256) {
    float4 vv = reinterpret_cast<const float4*>(pos_emb)[i];
    int w = i * 4;
    int f = w & 255;
    int dst = (w & ~255) + (f ^ ((f >> 5) << 2));
    *reinterpret_cast<float4*>(pe + dst) = vv;
  }

  const int t = threadIdx.x;
  const int half = t & 1, h = (t >> 1) & 7, pl = t >> 4;
  const int id = blockIdx.x;
  const int b = id & 7;
  const int local = id >> 3;
  const int bx = local & 31, by = local >> 5;
  const int xx = bx * 4 + (pl & 3);
  const int yy = by * 4 + (pl >> 2);
  const int yc = min(max(yy, 2), 125), xc = min(max(xx, 2), 125);
  const int fo = h * 32 + half * 16;
  const int hx4 = h << 2;
  const size_t pbase = ((size_t)((b * 128 + yy) * 128 + xx)) * 256 + fo;
  const size_t cbase = ((size_t)((b * 128 + yc) * 128 + xc)) * 256 + fo;
  const float SCALE = 0.17677669529663689f;

  float q[16];
  {
    v8s q0 = *reinterpret_cast<const v8s*>(Qb + pbase);
    v8s q1 = *reinterpret_cast<const v8s*>(Qb + pbase + 8);
#pragma unroll
    for (int e = 0; e < 8; ++e) { q[e] = bf2f(q0[e]); q[8 + e] = bf2f(q1[e]); }
  }
  __syncthreads();

  float l = 0.f;
  float oa[16];
#pragma unroll
  for (int f = 0; f < 16; ++f) oa[f] = 0.f;

  const short* kb = Kb + cbase;
  const short* vb = Vb + cbase;
  const float* pb = pe + h * 32;
  const int j0 = (half * 16) ^ hx4;
  const int j1 = (half * 16 + 4) ^ hx4;
  const int j2 = (half * 16 + 8) ^ hx4;
  const int j3 = (half * 16 + 12) ^ hx4;

  // depth-1 prefetch: next-offset K/V loads issued before current compute
  v8s kn0, kn1, vn0, vn1;
  {
    const short* kp = kb + (-2 * 128 - 2) * 256;
    const short* vp = vb + (-2 * 128 - 2) * 256;
    kn0 = *reinterpret_cast<const v8s*>(kp);
    kn1 = *reinterpret_cast<const v8s*>(kp + 8);
    vn0 = *reinterpret_cast<const v8s*>(vp);
    vn1 = *reinterpret_cast<const v8s*>(vp + 8);
  }

#pragma unroll 1
  for (int dy = -2; dy <= 2; ++dy) {
    const float* prow = pb + ((dy + 2) * 5) * 256;
#pragma unroll 1
    for (int dx = -2; dx <= 2; ++dx) {
      v8s k0 = kn0, k1 = kn1, v0 = vn0, v1 = vn1;
      // issue next offset's loads (uniform branch; skipped only on the last offset)
      int ndx = dx + 1, ndy = dy;
      if (ndx > 2) { ndx = -2; ndy = dy + 1; }
      if (ndy <= 2) {
        const short* kp2 = kb + (ndy * 128 + ndx) * 256;
        const short* vp2 = vb + (ndy * 128 + ndx) * 256;
        kn0 = *reinterpret_cast<const v8s*>(kp2);
        kn1 = *reinterpret_cast<const v8s*>(kp2 + 8);
        vn0 = *reinterpret_cast<const v8s*>(vp2);
        vn1 = *reinterpret_cast<const v8s*>(vp2 + 8);
      }
      const float* pp = prow + (dx + 2) * 256;
      float4 p0 = *reinterpret_cast<const float4*>(pp + j0);
      float4 p1 = *reinterpret_cast<const float4*>(pp + j1);
      float4 p2 = *reinterpret_cast<const float4*>(pp + j2);
      float4 p3 = *reinterpret_cast<const float4*>(pp + j3);
      float d0 = 0.f, d1 = 0.f, d2 = 0.f, d3 = 0.f;
#pragma unroll
      for (int e = 0; e < 4; ++e) {
        d0 = fmaf(q[e], bf2f(k0[e]), d0);
        d1 = fmaf(q[4 + e], bf2f(k0[4 + e]), d1);
        d2 = fmaf(q[8 + e], bf2f(k1[e]), d2);
        d3 = fmaf(q[12 + e], bf2f(k1[4 + e]), d3);
      }
      d0 = fmaf(q[0], p0.x, d0); d0 = fmaf(q[1], p0.y, d0);
      d0 = fmaf(q[2], p0.z, d0); d0 = fmaf(q[3], p0.w, d0);
      d1 = fmaf(q[4], p1.x, d1); d1 = fmaf(q[5], p1.y, d1);
      d1 = fmaf(q[6], p1.z, d1); d1 = fmaf(q[7], p1.w, d1);
      d2 = fmaf(q[8], p2.x, d2); d2 = fmaf(q[9], p2.y, d2);
      d2 = fmaf(q[10], p2.z, d2); d2 = fmaf(q[11], p2.w, d2);
      d3 = fmaf(q[12], p3.x, d3); d3 = fmaf(q[13], p3.y, d3);
      d3 = fmaf(q[14], p3.z, d3); d3 = fmaf(q[15], p3.w, d3);
      float part = ((d0 + d1) + (d2 + d3)) * SCALE;
      float full = part + __shfl_xor(part, 1);
      float w = __expf(full);
      l += w;
#pragma unroll
      for (int e = 0; e < 8; ++e) oa[e] = fmaf(w, bf2f(v0[e]), oa[e]);
#pragma unroll
      for (int e = 0; e < 8; ++e) oa[8 + e] = fmaf(w, bf2f(v1[e]), oa[8 + e]);
    }
  }

  float inv = 1.f / l;
  v8s o0, o1;
#pragma unroll
  for (int e = 0; e < 8; ++e) { o0[e] = f2bf(oa[e] * inv); o1[e] = f2bf(oa[8 + e] * inv); }
  *reinterpret_cast<v8s*>(ACC + pbase) = o0;
  *reinterpret_cast<v8s*>(ACC + pbase + 8) = o1;
}

// ---------------- output projection GEMM: R8 known-good (single-buf, full drains) ----------------
__launch_bounds__(256, 3)
__global__ void out_gemm(const short* __restrict__ A, const short* __restrict__ WoT,
                         float* __restrict__ out) {
  __shared__ short As[128 * 64];
  __shared__ short Bs[128 * 64];
  const int t = threadIdx.x;
  const int bi = blockIdx.x;
  const int xcd = bi & 7;
  const int j = bi >> 3;               // 0..127
  const int mgl = j / 2, nt = j % 2;
  const int mtg = xcd * 64 + mgl;      // 0..511, bijective
  const int m0 = mtg * 256;            // 2 m-tiles of 128 rows
  const int n0 = nt * 128;
  const int wave = t >> 6, lane = t & 63;
  const int wm = (wave & 1) * 64, wn = (wave >> 1) * 64;
  const int lr = lane & 15, g = lane >> 4;

  const int ro = lane >> 3;
  const int colb = ((lane & 7) * 16) ^ (ro << 4);
  const char* aSrc0 = reinterpret_cast<const char*>(A + (size_t)(m0 + ro) * 256) + colb;
  const char* bSrc  = reinterpret_cast<const char*>(WoT + (size_t)(n0 + ro) * 256) + colb;

#pragma unroll 1
  for (int u = 0; u < 2; ++u) {
    const char* aSrc = aSrc0 + (size_t)u * 128 * 512;

    v4f acc[4][4];
#pragma unroll
    for (int i = 0; i < 4; ++i)
#pragma unroll
      for (int jj = 0; jj < 4; ++jj) acc[i][jj] = (v4f){0.f, 0.f, 0.f, 0.f};

#pragma unroll 1
    for (int ks = 0; ks < 4; ++ks) {
      __syncthreads();
#pragma unroll
      for (int c = 0; c < 4; ++c) {
        int cc = wave * 4 + c;
        gld16(aSrc + (size_t)cc * 8 * 512 + ks * 128, (char*)As + cc * 1024);
        gld16(bSrc + (size_t)cc * 8 * 512 + ks * 128, (char*)Bs + cc * 1024);
      }
      __syncthreads();
#pragma unroll
      for (int kk = 0; kk < 2; ++kk) {
        v8s af[4], bfr[4];
#pragma unroll
        for (int i = 0; i < 4; ++i) {
          int row = wm + i * 16 + lr;
          int byte = (row * 128 + kk * 64 + g * 16) ^ ((row & 7) << 4);
          af[i] = *reinterpret_cast<const v8s*>(reinterpret_cast<const char*>(As) + byte);
        }
#pragma unroll
        for (int jj = 0; jj < 4; ++jj) {
          int rn = wn + jj * 16 + lr;
          int byte = (rn * 128 + kk * 64 + g * 16) ^ ((rn & 7) << 4);
          bfr[jj] = *reinterpret_cast<const v8s*>(reinterpret_cast<const char*>(Bs) + byte);
        }
#pragma unroll
        for (int i = 0; i < 4; ++i)
#pragma unroll
          for (int jj = 0; jj < 4; ++jj)
            acc[i][jj] = __builtin_amdgcn_mfma_f32_16x16x32_bf16(af[i], bfr[jj], acc[i][jj], 0, 0, 0);
      }
    }

#pragma unroll
    for (int i = 0; i < 4; ++i) {
#pragma unroll
      for (int jj = 0; jj < 4; ++jj) {
        int colg = n0 + wn + jj * 16 + lr;
#pragma unroll
        for (int r = 0; r < 4; ++r) {
          int p = m0 + u * 128 + wm + i * 16 + g * 4 + r;
          out[(size_t)p * 256 + colg] = acc[i][jj][r];
        }
      }
    }
  }
}

extern "C" void kernel_launch(void* const* d_in, const int* in_sizes, int n_in,
                              void* d_out, int out_size, void* d_ws, size_t ws_size,
                              hipStream_t stream) {
  const float* x       = (const float*)d_in[0];
  const float* Wq      = (const float*)d_in[1];
  const float* Wk      = (const float*)d_in[2];
  const float* Wv      = (const float*)d_in[3];
  const float* Wout    = (const float*)d_in[4];
  const float* pos_emb = (const float*)d_in[5];
  float* out = (float*)d_out;

  char* ws = (char*)d_ws;
  short* WcT  = (short*)ws;                       // 768*256*2   = 393216 B
  short* WoT  = (short*)(ws + 393216);            // 256*256*2   = 131072 B
  short* Qb   = (short*)(ws + 524288);            // 131072*256*2 each
  short* Kb   = Qb + (size_t)131072 * 256;
  short* Vb   = Kb + (size_t)131072 * 256;
  short* ACCb = Vb + (size_t)131072 * 256;
  short* xb   = ACCb;   // alias: xb used only before attn writes ACCb

  prep_weights<<<768, 256, 0, stream>>>(Wq, Wk, Wv, Wout, WcT, WoT);
  x_cast<<<4096, 256, 0, stream>>>(x, xb);
  proj_gemm<<<1536, 256, 0, stream>>>(xb, WcT, pos_emb, Qb, Kb, Vb);
  attn_kernel<<<8192, 256, 0, stream>>>(Qb, Kb, Vb, pos_emb, ACCb);
  out_gemm<<<1024, 256, 0, stream>>>(ACCb, WoT, out);
}

// Round 13
// 375.845 us; speedup vs baseline: 1.3386x; 1.3386x over previous
//
#include <hip/hip_runtime.h>

#define DEVI __device__ __forceinline__

typedef short v8s __attribute__((ext_vector_type(8)));
typedef float v4f __attribute__((ext_vector_type(4)));
typedef unsigned short u16;

typedef __attribute__((address_space(3))) unsigned int lds_u32;
typedef const __attribute__((address_space(1))) unsigned int glb_u32;

DEVI float bf2f(short s) {
  union { unsigned u; float f; } cv;
  cv.u = ((unsigned)(u16)s) << 16;
  return cv.f;
}
DEVI short f2bf(float f) {
  union { float f; unsigned u; } cv; cv.f = f;
  unsigned u = cv.u;
  return (short)((u + 0x7FFFu + ((u >> 16) & 1u)) >> 16);
}
DEVI void gld16(const void* g, void* l) {
  __builtin_amdgcn_global_load_lds((glb_u32*)g, (lds_u32*)l, 16, 0, 0);
}

// ---------------- prep: transpose + cast weights to bf16 ----------------
__global__ void prep_weights(const float* __restrict__ Wq, const float* __restrict__ Wk,
                             const float* __restrict__ Wv, const float* __restrict__ Wout,
                             short* __restrict__ WcT, short* __restrict__ WoT) {
  int n = blockIdx.x;
  int k = threadIdx.x;
  float v;
  if (n < 256)      v = Wq[k * 256 + n];
  else if (n < 512) v = Wk[k * 256 + (n - 256)];
  else              v = Wv[k * 256 + (n - 512)];
  WcT[n * 256 + k] = f2bf(v);
  if (n < 256) WoT[n * 256 + k] = f2bf(Wout[k * 256 + n]);
}

// ---------------- x -> bf16 cast ----------------
__global__ void x_cast(const float* __restrict__ x, short* __restrict__ xb) {
  for (size_t gidx = (size_t)blockIdx.x * 256 + threadIdx.x; gidx < 4194304;
       gidx += (size_t)4096 * 256) {
    const float4* src = reinterpret_cast<const float4*>(x + gidx * 8);
    float4 a = src[0], c = src[1];
    v8s pk;
    pk[0] = f2bf(a.x); pk[1] = f2bf(a.y); pk[2] = f2bf(a.z); pk[3] = f2bf(a.w);
    pk[4] = f2bf(c.x); pk[5] = f2bf(c.y); pk[6] = f2bf(c.z); pk[7] = f2bf(c.w);
    *reinterpret_cast<v8s*>(xb + gidx * 8) = pk;
  }
}

// ---------------- QKV projection: 256x256 tile, 8 waves, BK=64, dbuf ----------------
// Per K-step: 64 MFMA/wave (~614 cy/SIMD) >> staging latency -> drains are covered.
// grid 1536 x 512t = 512 m-tiles x 3 n-tiles, XCD-chunked (3 nt of one A-panel co-XCD).
__launch_bounds__(512, 2)
__global__ void proj_gemm(const short* __restrict__ xb, const short* __restrict__ WcT,
                          const float* __restrict__ pos_emb,
                          short* __restrict__ Qb, short* __restrict__ Kb,
                          short* __restrict__ Vb) {
  __shared__ short As[2][256 * 64];   // 2 x 32 KB
  __shared__ short Bs[2][256 * 64];   // 2 x 32 KB -> 128 KB total
  const int t = threadIdx.x;
  const int bi = blockIdx.x;
  const int xcd = bi & 7;
  const int j = bi >> 3;               // 0..191
  const int mtl = j / 3, nt = j % 3;
  const int mt = xcd * 64 + mtl;       // 0..511, bijective (1536 % 8 == 0)
  const int m0 = mt * 256, n0 = nt * 256;
  const int wave = t >> 6, lane = t & 63;
  const int wm = (wave >> 2) * 128, wn = (wave & 3) * 64;   // 2M x 4N waves
  const int lr = lane & 15, g = lane >> 4;

  // DMA source (pre-swizzled involution ^(ro<<4)); LDS linear 128B rows
  const int ro = lane >> 3;
  const int colb = ((lane & 7) * 16) ^ (ro << 4);
  const char* aSrc0 = reinterpret_cast<const char*>(xb + (size_t)(m0 + ro) * 256) + colb;
  const char* bSrc0 = reinterpret_cast<const char*>(WcT + (size_t)(n0 + ro) * 256) + colb;

  auto stage = [&](int buf, int ks) {
#pragma unroll
    for (int c = 0; c < 4; ++c) {
      int cc = wave * 4 + c;           // 32 chunks of 8 rows
      gld16(aSrc0 + (size_t)cc * 8 * 512 + ks * 128, (char*)As[buf] + cc * 1024);
      gld16(bSrc0 + (size_t)cc * 8 * 512 + ks * 128, (char*)Bs[buf] + cc * 1024);
    }
  };

  v4f acc[8][4];
#pragma unroll
  for (int i = 0; i < 8; ++i)
#pragma unroll
    for (int jj = 0; jj < 4; ++jj) acc[i][jj] = (v4f){0.f, 0.f, 0.f, 0.f};

  stage(0, 0);
  __syncthreads();

#pragma unroll 1
  for (int s = 0; s < 4; ++s) {
    const int buf = s & 1;
    if (s < 3) stage(buf ^ 1, s + 1);   // lands under ~614 cy of compute below

    const char* aB = (const char*)As[buf];
    const char* bB = (const char*)Bs[buf];
#pragma unroll
    for (int kk = 0; kk < 2; ++kk) {
      v8s bfr[4];
#pragma unroll
      for (int jj = 0; jj < 4; ++jj) {
        int rn = wn + jj * 16 + lr;
        bfr[jj] = *reinterpret_cast<const v8s*>(
            bB + ((rn * 128 + kk * 64 + g * 16) ^ ((rn & 7) << 4)));
      }
#pragma unroll
      for (int i = 0; i < 8; ++i) {
        int row = wm + i * 16 + lr;
        v8s af = *reinterpret_cast<const v8s*>(
            aB + ((row * 128 + kk * 64 + g * 16) ^ ((row & 7) << 4)));
#pragma unroll
        for (int jj = 0; jj < 4; ++jj)
          acc[i][jj] = __builtin_amdgcn_mfma_f32_16x16x32_bf16(af, bfr[jj], acc[i][jj], 0, 0, 0);
      }
    }
    __syncthreads();   // next stage landed (had full compute to arrive) + buffer handoff
  }

  // epilogue: whole block writes one of Q/K/V (uniform by nt)
  short* dst = (nt == 0) ? Qb : (nt == 1) ? Kb : Vb;
#pragma unroll
  for (int i = 0; i < 8; ++i) {
#pragma unroll
    for (int jj = 0; jj < 4; ++jj) {
      int col = wn + jj * 16 + lr;
#pragma unroll
      for (int r = 0; r < 4; ++r) {
        int p = m0 + wm + i * 16 + g * 4 + r;
        float v = acc[i][jj][r];
        if (nt == 0) {
          int yy = (p >> 7) & 127, xx = p & 127;
          int qi = (yy - min(max(yy, 2), 125) + 2) * 5 + (xx - min(max(xx, 2), 125) + 2);
          v += pos_emb[qi * 256 + col];
        }
        dst[(size_t)p * 256 + col] = f2bf(v);
      }
    }
  }
}

// ---------------- attention: split-F + depth-1 K/V register prefetch ----------------
__launch_bounds__(256, 4)
__global__ void attn_kernel(const short* __restrict__ Qb, const short* __restrict__ Kb,
                            const short* __restrict__ Vb, const float* __restrict__ pos_emb,
                            short* __restrict__ ACC) {
  __shared__ float pe[25 * 256];
  for (int i = threadIdx.x; i < 1600; i += 256) {
    float4 vv = reinterpret_cast<const float4*>(pos_emb)[i];
    int w = i * 4;
    int f = w & 255;
    int dst = (w & ~255) + (f ^ ((f >> 5) << 2));
    *reinterpret_cast<float4*>(pe + dst) = vv;
  }

  const int t = threadIdx.x;
  const int half = t & 1, h = (t >> 1) & 7, pl = t >> 4;
  const int id = blockIdx.x;
  const int b = id & 7;
  const int local = id >> 3;
  const int bx = local & 31, by = local >> 5;
  const int xx = bx * 4 + (pl & 3);
  const int yy = by * 4 + (pl >> 2);
  const int yc = min(max(yy, 2), 125), xc = min(max(xx, 2), 125);
  const int fo = h * 32 + half * 16;
  const int hx4 = h << 2;
  const size_t pbase = ((size_t)((b * 128 + yy) * 128 + xx)) * 256 + fo;
  const size_t cbase = ((size_t)((b * 128 + yc) * 128 + xc)) * 256 + fo;
  const float SCALE = 0.17677669529663689f;

  float q[16];
  {
    v8s q0 = *reinterpret_cast<const v8s*>(Qb + pbase);
    v8s q1 = *reinterpret_cast<const v8s*>(Qb + pbase + 8);
#pragma unroll
    for (int e = 0; e < 8; ++e) { q[e] = bf2f(q0[e]); q[8 + e] = bf2f(q1[e]); }
  }
  __syncthreads();

  float l = 0.f;
  float oa[16];
#pragma unroll
  for (int f = 0; f < 16; ++f) oa[f] = 0.f;

  const short* kb = Kb + cbase;
  const short* vb = Vb + cbase;
  const float* pb = pe + h * 32;
  const int j0 = (half * 16) ^ hx4;
  const int j1 = (half * 16 + 4) ^ hx4;
  const int j2 = (half * 16 + 8) ^ hx4;
  const int j3 = (half * 16 + 12) ^ hx4;

  v8s kn0, kn1, vn0, vn1;
  {
    const short* kp = kb + (-2 * 128 - 2) * 256;
    const short* vp = vb + (-2 * 128 - 2) * 256;
    kn0 = *reinterpret_cast<const v8s*>(kp);
    kn1 = *reinterpret_cast<const v8s*>(kp + 8);
    vn0 = *reinterpret_cast<const v8s*>(vp);
    vn1 = *reinterpret_cast<const v8s*>(vp + 8);
  }

#pragma unroll 1
  for (int dy = -2; dy <= 2; ++dy) {
    const float* prow = pb + ((dy + 2) * 5) * 256;
#pragma unroll 1
    for (int dx = -2; dx <= 2; ++dx) {
      v8s k0 = kn0, k1 = kn1, v0 = vn0, v1 = vn1;
      int ndx = dx + 1, ndy = dy;
      if (ndx > 2) { ndx = -2; ndy = dy + 1; }
      if (ndy <= 2) {
        const short* kp2 = kb + (ndy * 128 + ndx) * 256;
        const short* vp2 = vb + (ndy * 128 + ndx) * 256;
        kn0 = *reinterpret_cast<const v8s*>(kp2);
        kn1 = *reinterpret_cast<const v8s*>(kp2 + 8);
        vn0 = *reinterpret_cast<const v8s*>(vp2);
        vn1 = *reinterpret_cast<const v8s*>(vp2 + 8);
      }
      const float* pp = prow + (dx + 2) * 256;
      float4 p0 = *reinterpret_cast<const float4*>(pp + j0);
      float4 p1 = *reinterpret_cast<const float4*>(pp + j1);
      float4 p2 = *reinterpret_cast<const float4*>(pp + j2);
      float4 p3 = *reinterpret_cast<const float4*>(pp + j3);
      float d0 = 0.f, d1 = 0.f, d2 = 0.f, d3 = 0.f;
#pragma unroll
      for (int e = 0; e < 4; ++e) {
        d0 = fmaf(q[e], bf2f(k0[e]), d0);
        d1 = fmaf(q[4 + e], bf2f(k0[4 + e]), d1);
        d2 = fmaf(q[8 + e], bf2f(k1[e]), d2);
        d3 = fmaf(q[12 + e], bf2f(k1[4 + e]), d3);
      }
      d0 = fmaf(q[0], p0.x, d0); d0 = fmaf(q[1], p0.y, d0);
      d0 = fmaf(q[2], p0.z, d0); d0 = fmaf(q[3], p0.w, d0);
      d1 = fmaf(q[4], p1.x, d1); d1 = fmaf(q[5], p1.y, d1);
      d1 = fmaf(q[6], p1.z, d1); d1 = fmaf(q[7], p1.w, d1);
      d2 = fmaf(q[8], p2.x, d2); d2 = fmaf(q[9], p2.y, d2);
      d2 = fmaf(q[10], p2.z, d2); d2 = fmaf(q[11], p2.w, d2);
      d3 = fmaf(q[12], p3.x, d3); d3 = fmaf(q[13], p3.y, d3);
      d3 = fmaf(q[14], p3.z, d3); d3 = fmaf(q[15], p3.w, d3);
      float part = ((d0 + d1) + (d2 + d3)) * SCALE;
      float full = part + __shfl_xor(part, 1);
      float w = __expf(full);
      l += w;
#pragma unroll
      for (int e = 0; e < 8; ++e) oa[e] = fmaf(w, bf2f(v0[e]), oa[e]);
#pragma unroll
      for (int e = 0; e < 8; ++e) oa[8 + e] = fmaf(w, bf2f(v1[e]), oa[8 + e]);
    }
  }

  float inv = 1.f / l;
  v8s o0, o1;
#pragma unroll
  for (int e = 0; e < 8; ++e) { o0[e] = f2bf(oa[e] * inv); o1[e] = f2bf(oa[8 + e] * inv); }
  *reinterpret_cast<v8s*>(ACC + pbase) = o0;
  *reinterpret_cast<v8s*>(ACC + pbase + 8) = o1;
}

// ---------------- output projection: 256x256 tile, 8 waves, BK=64, dbuf ----------------
// grid 512 x 512t = 512 m-tiles x 1 n-tile, XCD-chunked.
__launch_bounds__(512, 2)
__global__ void out_gemm(const short* __restrict__ A, const short* __restrict__ WoT,
                         float* __restrict__ out) {
  __shared__ short As[2][256 * 64];
  __shared__ short Bs[2][256 * 64];
  const int t = threadIdx.x;
  const int bi = blockIdx.x;
  const int xcd = bi & 7;
  const int mt = xcd * 64 + (bi >> 3);   // 0..511, bijective (512 % 8 == 0)
  const int m0 = mt * 256;
  const int wave = t >> 6, lane = t & 63;
  const int wm = (wave >> 2) * 128, wn = (wave & 3) * 64;
  const int lr = lane & 15, g = lane >> 4;

  const int ro = lane >> 3;
  const int colb = ((lane & 7) * 16) ^ (ro << 4);
  const char* aSrc0 = reinterpret_cast<const char*>(A + (size_t)(m0 + ro) * 256) + colb;
  const char* bSrc0 = reinterpret_cast<const char*>(WoT + (size_t)ro * 256) + colb;

  auto stage = [&](int buf, int ks) {
#pragma unroll
    for (int c = 0; c < 4; ++c) {
      int cc = wave * 4 + c;
      gld16(aSrc0 + (size_t)cc * 8 * 512 + ks * 128, (char*)As[buf] + cc * 1024);
      gld16(bSrc0 + (size_t)cc * 8 * 512 + ks * 128, (char*)Bs[buf] + cc * 1024);
    }
  };

  v4f acc[8][4];
#pragma unroll
  for (int i = 0; i < 8; ++i)
#pragma unroll
    for (int jj = 0; jj < 4; ++jj) acc[i][jj] = (v4f){0.f, 0.f, 0.f, 0.f};

  stage(0, 0);
  __syncthreads();

#pragma unroll 1
  for (int s = 0; s < 4; ++s) {
    const int buf = s & 1;
    if (s < 3) stage(buf ^ 1, s + 1);

    const char* aB = (const char*)As[buf];
    const char* bB = (const char*)Bs[buf];
#pragma unroll
    for (int kk = 0; kk < 2; ++kk) {
      v8s bfr[4];
#pragma unroll
      for (int jj = 0; jj < 4; ++jj) {
        int rn = wn + jj * 16 + lr;
        bfr[jj] = *reinterpret_cast<const v8s*>(
            bB + ((rn * 128 + kk * 64 + g * 16) ^ ((rn & 7) << 4)));
      }
#pragma unroll
      for (int i = 0; i < 8; ++i) {
        int row = wm + i * 16 + lr;
        v8s af = *reinterpret_cast<const v8s*>(
            aB + ((row * 128 + kk * 64 + g * 16) ^ ((row & 7) << 4)));
#pragma unroll
        for (int jj = 0; jj < 4; ++jj)
          acc[i][jj] = __builtin_amdgcn_mfma_f32_16x16x32_bf16(af, bfr[jj], acc[i][jj], 0, 0, 0);
      }
    }
    __syncthreads();
  }

#pragma unroll
  for (int i = 0; i < 8; ++i) {
#pragma unroll
    for (int jj = 0; jj < 4; ++jj) {
      int col = wn + jj * 16 + lr;
#pragma unroll
      for (int r = 0; r < 4; ++r) {
        int p = m0 + wm + i * 16 + g * 4 + r;
        out[(size_t)p * 256 + col] = acc[i][jj][r];
      }
    }
  }
}

extern "C" void kernel_launch(void* const* d_in, const int* in_sizes, int n_in,
                              void* d_out, int out_size, void* d_ws, size_t ws_size,
                              hipStream_t stream) {
  const float* x       = (const float*)d_in[0];
  const float* Wq      = (const float*)d_in[1];
  const float* Wk      = (const float*)d_in[2];
  const float* Wv      = (const float*)d_in[3];
  const float* Wout    = (const float*)d_in[4];
  const float* pos_emb = (const float*)d_in[5];
  float* out = (float*)d_out;

  char* ws = (char*)d_ws;
  short* WcT  = (short*)ws;                       // 768*256*2   = 393216 B
  short* WoT  = (short*)(ws + 393216);            // 256*256*2   = 131072 B
  short* Qb   = (short*)(ws + 524288);            // 131072*256*2 each
  short* Kb   = Qb + (size_t)131072 * 256;
  short* Vb   = Kb + (size_t)131072 * 256;
  short* ACCb = Vb + (size_t)131072 * 256;
  short* xb   = ACCb;   // alias: xb used only before attn writes ACCb

  prep_weights<<<768, 256, 0, stream>>>(Wq, Wk, Wv, Wout, WcT, WoT);
  x_cast<<<4096, 256, 0, stream>>>(x, xb);
  proj_gemm<<<1536, 512, 0, stream>>>(xb, WcT, pos_emb, Qb, Kb, Vb);
  attn_kernel<<<8192, 256, 0, stream>>>(Qb, Kb, Vb, pos_emb, ACCb);
  out_gemm<<<512, 512, 0, stream>>>(ACCb, WoT, out);
}

// Round 14
// 358.563 us; speedup vs baseline: 1.4031x; 1.0482x over previous
//
#include <hip/hip_runtime.h>

#define DEVI __device__ __forceinline__

typedef short v8s __attribute__((ext_vector_type(8)));
typedef float v4f __attribute__((ext_vector_type(4)));
typedef unsigned short u16;

typedef __attribute__((address_space(3))) unsigned int lds_u32;
typedef const __attribute__((address_space(1))) unsigned int glb_u32;

DEVI float bf2f(short s) {
  union { unsigned u; float f; } cv;
  cv.u = ((unsigned)(u16)s) << 16;
  return cv.f;
}
DEVI short f2bf(float f) {
  union { float f; unsigned u; } cv; cv.f = f;
  unsigned u = cv.u;
  return (short)((u + 0x7FFFu + ((u >> 16) & 1u)) >> 16);
}
DEVI unsigned cvtpk(float lo, float hi) {  // [bf16(hi)|bf16(lo)], RNE (guide T12)
  unsigned r;
  asm("v_cvt_pk_bf16_f32 %0, %1, %2" : "=v"(r) : "v"(lo), "v"(hi));
  return r;
}
DEVI void gld16(const void* g, void* l) {
  __builtin_amdgcn_global_load_lds((glb_u32*)g, (lds_u32*)l, 16, 0, 0);
}

// ---------------- prep: transpose + cast weights to bf16 ----------------
__global__ void prep_weights(const float* __restrict__ Wq, const float* __restrict__ Wk,
                             const float* __restrict__ Wv, const float* __restrict__ Wout,
                             short* __restrict__ WcT, short* __restrict__ WoT) {
  int n = blockIdx.x;
  int k = threadIdx.x;
  float v;
  if (n < 256)      v = Wq[k * 256 + n];
  else if (n < 512) v = Wk[k * 256 + (n - 256)];
  else              v = Wv[k * 256 + (n - 512)];
  WcT[n * 256 + k] = f2bf(v);
  if (n < 256) WoT[n * 256 + k] = f2bf(Wout[k * 256 + n]);
}

// ---------------- x -> bf16 cast ----------------
__global__ void x_cast(const float* __restrict__ x, short* __restrict__ xb) {
  for (size_t gidx = (size_t)blockIdx.x * 256 + threadIdx.x; gidx < 4194304;
       gidx += (size_t)4096 * 256) {
    const float4* src = reinterpret_cast<const float4*>(x + gidx * 8);
    float4 a = src[0], c = src[1];
    v8s pk;
    pk[0] = f2bf(a.x); pk[1] = f2bf(a.y); pk[2] = f2bf(a.z); pk[3] = f2bf(a.w);
    pk[4] = f2bf(c.x); pk[5] = f2bf(c.y); pk[6] = f2bf(c.z); pk[7] = f2bf(c.w);
    *reinterpret_cast<v8s*>(xb + gidx * 8) = pk;
  }
}

// ---------------- QKV projection: 256x256 tile, swapped-operand MFMA, wide stores ----------------
// mfma(bfr, af): D row-formula -> n (4 consecutive per thread), col(lane&15) -> p.
__launch_bounds__(512, 2)
__global__ void proj_gemm(const short* __restrict__ xb, const short* __restrict__ WcT,
                          const float* __restrict__ pos_emb,
                          short* __restrict__ Qb, short* __restrict__ Kb,
                          short* __restrict__ Vb) {
  __shared__ short As[2][256 * 64];
  __shared__ short Bs[2][256 * 64];
  const int t = threadIdx.x;
  const int bi = blockIdx.x;
  const int xcd = bi & 7;
  const int j = bi >> 3;               // 0..191
  const int mtl = j / 3, nt = j % 3;
  const int mt = xcd * 64 + mtl;       // 0..511, bijective
  const int m0 = mt * 256, n0 = nt * 256;
  const int wave = t >> 6, lane = t & 63;
  const int wm = (wave >> 2) * 128, wn = (wave & 3) * 64;
  const int lr = lane & 15, g = lane >> 4;

  const int ro = lane >> 3;
  const int colb = ((lane & 7) * 16) ^ (ro << 4);
  const char* aSrc0 = reinterpret_cast<const char*>(xb + (size_t)(m0 + ro) * 256) + colb;
  const char* bSrc0 = reinterpret_cast<const char*>(WcT + (size_t)(n0 + ro) * 256) + colb;

  auto stage = [&](int buf, int ks) {
#pragma unroll
    for (int c = 0; c < 4; ++c) {
      int cc = wave * 4 + c;
      gld16(aSrc0 + (size_t)cc * 8 * 512 + ks * 128, (char*)As[buf] + cc * 1024);
      gld16(bSrc0 + (size_t)cc * 8 * 512 + ks * 128, (char*)Bs[buf] + cc * 1024);
    }
  };

  v4f acc[8][4];
#pragma unroll
  for (int i = 0; i < 8; ++i)
#pragma unroll
    for (int jj = 0; jj < 4; ++jj) acc[i][jj] = (v4f){0.f, 0.f, 0.f, 0.f};

  stage(0, 0);
  __syncthreads();

#pragma unroll 1
  for (int s = 0; s < 4; ++s) {
    const int buf = s & 1;
    if (s < 3) stage(buf ^ 1, s + 1);

    const char* aB = (const char*)As[buf];
    const char* bB = (const char*)Bs[buf];
#pragma unroll
    for (int kk = 0; kk < 2; ++kk) {
      v8s bfr[4];
#pragma unroll
      for (int jj = 0; jj < 4; ++jj) {
        int rn = wn + jj * 16 + lr;
        bfr[jj] = *reinterpret_cast<const v8s*>(
            bB + ((rn * 128 + kk * 64 + g * 16) ^ ((rn & 7) << 4)));
      }
#pragma unroll
      for (int i = 0; i < 8; ++i) {
        int row = wm + i * 16 + lr;
        v8s af = *reinterpret_cast<const v8s*>(
            aB + ((row * 128 + kk * 64 + g * 16) ^ ((row & 7) << 4)));
#pragma unroll
        for (int jj = 0; jj < 4; ++jj)
          acc[i][jj] = __builtin_amdgcn_mfma_f32_16x16x32_bf16(bfr[jj], af, acc[i][jj], 0, 0, 0);
      }
    }
    __syncthreads();
  }

  // epilogue: thread holds rows n = wn+jj*16+g*4+(0..3) at col p = m0+wm+i*16+lr
  short* dst = (nt == 0) ? Qb : (nt == 1) ? Kb : Vb;
#pragma unroll
  for (int i = 0; i < 8; ++i) {
    int p = m0 + wm + i * 16 + lr;
    int qi = 0;
    if (nt == 0) {
      int yy = (p >> 7) & 127, xx = p & 127;
      qi = (yy - min(max(yy, 2), 125) + 2) * 5 + (xx - min(max(xx, 2), 125) + 2);
    }
#pragma unroll
    for (int jj = 0; jj < 4; ++jj) {
      int nb = wn + jj * 16 + g * 4;   // block-local col, 4-aligned
      v4f a = acc[i][jj];
      if (nt == 0) {
        float4 pe4 = *reinterpret_cast<const float4*>(pos_emb + qi * 256 + nb);
        a[0] += pe4.x; a[1] += pe4.y; a[2] += pe4.z; a[3] += pe4.w;
      }
      uint2 pk;
      pk.x = cvtpk(a[0], a[1]);
      pk.y = cvtpk(a[2], a[3]);
      *reinterpret_cast<uint2*>(dst + (size_t)p * 256 + nb) = pk;
    }
  }
}

// ---------------- attention: split-F + depth-1 K/V prefetch (R13) + exp2 + cvtpk ----------------
__launch_bounds__(256, 4)
__global__ void attn_kernel(const short* __restrict__ Qb, const short* __restrict__ Kb,
                            const short* __restrict__ Vb, const float* __restrict__ pos_emb,
                            short* __restrict__ ACC) {
  __shared__ float pe[25 * 256];
  for (int i = threadIdx.x; i < 1600; i += 256) {
    float4 vv = reinterpret_cast<const float4*>(pos_emb)[i];
    int w = i * 4;
    int f = w & 255;
    int dst = (w & ~255) + (f ^ ((f >> 5) << 2));
    *reinterpret_cast<float4*>(pe + dst) = vv;
  }

  const int t = threadIdx.x;
  const int half = t & 1, h = (t >> 1) & 7, pl = t >> 4;
  const int id = blockIdx.x;
  const int b = id & 7;
  const int local = id >> 3;
  const int bx = local & 31, by = local >> 5;
  const int xx = bx * 4 + (pl & 3);
  const int yy = by * 4 + (pl >> 2);
  const int yc = min(max(yy, 2), 125), xc = min(max(xx, 2), 125);
  const int fo = h * 32 + half * 16;
  const int hx4 = h << 2;
  const size_t pbase = ((size_t)((b * 128 + yy) * 128 + xx)) * 256 + fo;
  const size_t cbase = ((size_t)((b * 128 + yc) * 128 + xc)) * 256 + fo;
  const float SCALE2 = 0.17677669529663689f * 1.4426950408889634f;  // 1/sqrt(32) * log2(e)

  float q[16];
  {
    v8s q0 = *reinterpret_cast<const v8s*>(Qb + pbase);
    v8s q1 = *reinterpret_cast<const v8s*>(Qb + pbase + 8);
#pragma unroll
    for (int e = 0; e < 8; ++e) { q[e] = bf2f(q0[e]); q[8 + e] = bf2f(q1[e]); }
  }
  __syncthreads();

  float l = 0.f;
  float oa[16];
#pragma unroll
  for (int f = 0; f < 16; ++f) oa[f] = 0.f;

  const short* kb = Kb + cbase;
  const short* vb = Vb + cbase;
  const float* pb = pe + h * 32;
  const int j0 = (half * 16) ^ hx4;
  const int j1 = (half * 16 + 4) ^ hx4;
  const int j2 = (half * 16 + 8) ^ hx4;
  const int j3 = (half * 16 + 12) ^ hx4;

  v8s kn0, kn1, vn0, vn1;
  {
    const short* kp = kb + (-2 * 128 - 2) * 256;
    const short* vp = vb + (-2 * 128 - 2) * 256;
    kn0 = *reinterpret_cast<const v8s*>(kp);
    kn1 = *reinterpret_cast<const v8s*>(kp + 8);
    vn0 = *reinterpret_cast<const v8s*>(vp);
    vn1 = *reinterpret_cast<const v8s*>(vp + 8);
  }

#pragma unroll 1
  for (int dy = -2; dy <= 2; ++dy) {
    const float* prow = pb + ((dy + 2) * 5) * 256;
#pragma unroll 1
    for (int dx = -2; dx <= 2; ++dx) {
      v8s k0 = kn0, k1 = kn1, v0 = vn0, v1 = vn1;
      int ndx = dx + 1, ndy = dy;
      if (ndx > 2) { ndx = -2; ndy = dy + 1; }
      if (ndy <= 2) {
        const short* kp2 = kb + (ndy * 128 + ndx) * 256;
        const short* vp2 = vb + (ndy * 128 + ndx) * 256;
        kn0 = *reinterpret_cast<const v8s*>(kp2);
        kn1 = *reinterpret_cast<const v8s*>(kp2 + 8);
        vn0 = *reinterpret_cast<const v8s*>(vp2);
        vn1 = *reinterpret_cast<const v8s*>(vp2 + 8);
      }
      const float* pp = prow + (dx + 2) * 256;
      float4 p0 = *reinterpret_cast<const float4*>(pp + j0);
      float4 p1 = *reinterpret_cast<const float4*>(pp + j1);
      float4 p2 = *reinterpret_cast<const float4*>(pp + j2);
      float4 p3 = *reinterpret_cast<const float4*>(pp + j3);
      float d0 = 0.f, d1 = 0.f, d2 = 0.f, d3 = 0.f;
#pragma unroll
      for (int e = 0; e < 4; ++e) {
        d0 = fmaf(q[e], bf2f(k0[e]), d0);
        d1 = fmaf(q[4 + e], bf2f(k0[4 + e]), d1);
        d2 = fmaf(q[8 + e], bf2f(k1[e]), d2);
        d3 = fmaf(q[12 + e], bf2f(k1[4 + e]), d3);
      }
      d0 = fmaf(q[0], p0.x, d0); d0 = fmaf(q[1], p0.y, d0);
      d0 = fmaf(q[2], p0.z, d0); d0 = fmaf(q[3], p0.w, d0);
      d1 = fmaf(q[4], p1.x, d1); d1 = fmaf(q[5], p1.y, d1);
      d1 = fmaf(q[6], p1.z, d1); d1 = fmaf(q[7], p1.w, d1);
      d2 = fmaf(q[8], p2.x, d2); d2 = fmaf(q[9], p2.y, d2);
      d2 = fmaf(q[10], p2.z, d2); d2 = fmaf(q[11], p2.w, d2);
      d3 = fmaf(q[12], p3.x, d3); d3 = fmaf(q[13], p3.y, d3);
      d3 = fmaf(q[14], p3.z, d3); d3 = fmaf(q[15], p3.w, d3);
      float part = ((d0 + d1) + (d2 + d3)) * SCALE2;
      float full = part + __shfl_xor(part, 1);
      float w = exp2f(full);     // == expf(score*SCALE), log2e folded into SCALE2
      l += w;
#pragma unroll
      for (int e = 0; e < 8; ++e) oa[e] = fmaf(w, bf2f(v0[e]), oa[e]);
#pragma unroll
      for (int e = 0; e < 8; ++e) oa[8 + e] = fmaf(w, bf2f(v1[e]), oa[8 + e]);
    }
  }

  float inv = 1.f / l;
  uint4 o0, o1;
  o0.x = cvtpk(oa[0] * inv, oa[1] * inv);
  o0.y = cvtpk(oa[2] * inv, oa[3] * inv);
  o0.z = cvtpk(oa[4] * inv, oa[5] * inv);
  o0.w = cvtpk(oa[6] * inv, oa[7] * inv);
  o1.x = cvtpk(oa[8] * inv, oa[9] * inv);
  o1.y = cvtpk(oa[10] * inv, oa[11] * inv);
  o1.z = cvtpk(oa[12] * inv, oa[13] * inv);
  o1.w = cvtpk(oa[14] * inv, oa[15] * inv);
  *reinterpret_cast<uint4*>(ACC + pbase) = o0;
  *reinterpret_cast<uint4*>(ACC + pbase + 8) = o1;
}

// ---------------- output projection: 256x256 tile, swapped operands, float4 stores ----------------
__launch_bounds__(512, 2)
__global__ void out_gemm(const short* __restrict__ A, const short* __restrict__ WoT,
                         float* __restrict__ out) {
  __shared__ short As[2][256 * 64];
  __shared__ short Bs[2][256 * 64];
  const int t = threadIdx.x;
  const int bi = blockIdx.x;
  const int xcd = bi & 7;
  const int mt = xcd * 64 + (bi >> 3);
  const int m0 = mt * 256;
  const int wave = t >> 6, lane = t & 63;
  const int wm = (wave >> 2) * 128, wn = (wave & 3) * 64;
  const int lr = lane & 15, g = lane >> 4;

  const int ro = lane >> 3;
  const int colb = ((lane & 7) * 16) ^ (ro << 4);
  const char* aSrc0 = reinterpret_cast<const char*>(A + (size_t)(m0 + ro) * 256) + colb;
  const char* bSrc0 = reinterpret_cast<const char*>(WoT + (size_t)ro * 256) + colb;

  auto stage = [&](int buf, int ks) {
#pragma unroll
    for (int c = 0; c < 4; ++c) {
      int cc = wave * 4 + c;
      gld16(aSrc0 + (size_t)cc * 8 * 512 + ks * 128, (char*)As[buf] + cc * 1024);
      gld16(bSrc0 + (size_t)cc * 8 * 512 + ks * 128, (char*)Bs[buf] + cc * 1024);
    }
  };

  v4f acc[8][4];
#pragma unroll
  for (int i = 0; i < 8; ++i)
#pragma unroll
    for (int jj = 0; jj < 4; ++jj) acc[i][jj] = (v4f){0.f, 0.f, 0.f, 0.f};

  stage(0, 0);
  __syncthreads();

#pragma unroll 1
  for (int s = 0; s < 4; ++s) {
    const int buf = s & 1;
    if (s < 3) stage(buf ^ 1, s + 1);

    const char* aB = (const char*)As[buf];
    const char* bB = (const char*)Bs[buf];
#pragma unroll
    for (int kk = 0; kk < 2; ++kk) {
      v8s bfr[4];
#pragma unroll
      for (int jj = 0; jj < 4; ++jj) {
        int rn = wn + jj * 16 + lr;
        bfr[jj] = *reinterpret_cast<const v8s*>(
            bB + ((rn * 128 + kk * 64 + g * 16) ^ ((rn & 7) << 4)));
      }
#pragma unroll
      for (int i = 0; i < 8; ++i) {
        int row = wm + i * 16 + lr;
        v8s af = *reinterpret_cast<const v8s*>(
            aB + ((row * 128 + kk * 64 + g * 16) ^ ((row & 7) << 4)));
#pragma unroll
        for (int jj = 0; jj < 4; ++jj)
          acc[i][jj] = __builtin_amdgcn_mfma_f32_16x16x32_bf16(bfr[jj], af, acc[i][jj], 0, 0, 0);
      }
    }
    __syncthreads();
  }

#pragma unroll
  for (int i = 0; i < 8; ++i) {
    int p = m0 + wm + i * 16 + lr;
#pragma unroll
    for (int jj = 0; jj < 4; ++jj) {
      int nb = wn + jj * 16 + g * 4;
      float4 o;
      o.x = acc[i][jj][0]; o.y = acc[i][jj][1];
      o.z = acc[i][jj][2]; o.w = acc[i][jj][3];
      *reinterpret_cast<float4*>(out + (size_t)p * 256 + nb) = o;
    }
  }
}

extern "C" void kernel_launch(void* const* d_in, const int* in_sizes, int n_in,
                              void* d_out, int out_size, void* d_ws, size_t ws_size,
                              hipStream_t stream) {
  const float* x       = (const float*)d_in[0];
  const float* Wq      = (const float*)d_in[1];
  const float* Wk      = (const float*)d_in[2];
  const float* Wv      = (const float*)d_in[3];
  const float* Wout    = (const float*)d_in[4];
  const float* pos_emb = (const float*)d_in[5];
  float* out = (float*)d_out;

  char* ws = (char*)d_ws;
  short* WcT  = (short*)ws;                       // 768*256*2   = 393216 B
  short* WoT  = (short*)(ws + 393216);            // 256*256*2   = 131072 B
  short* Qb   = (short*)(ws + 524288);            // 131072*256*2 each
  short* Kb   = Qb + (size_t)131072 * 256;
  short* Vb   = Kb + (size_t)131072 * 256;
  short* ACCb = Vb + (size_t)131072 * 256;
  short* xb   = ACCb;   // alias: xb used only before attn writes ACCb

  prep_weights<<<768, 256, 0, stream>>>(Wq, Wk, Wv, Wout, WcT, WoT);
  x_cast<<<4096, 256, 0, stream>>>(x, xb);
  proj_gemm<<<1536, 512, 0, stream>>>(xb, WcT, pos_emb, Qb, Kb, Vb);
  attn_kernel<<<8192, 256, 0, stream>>>(Qb, Kb, Vb, pos_emb, ACCb);
  out_gemm<<<512, 512, 0, stream>>>(ACCb, WoT, out);
}

// Round 17
// 357.720 us; speedup vs baseline: 1.4064x; 1.0024x over previous
//
#include <hip/hip_runtime.h>

#define DEVI __device__ __forceinline__

typedef short v8s __attribute__((ext_vector_type(8)));
typedef float v4f __attribute__((ext_vector_type(4)));
typedef _Float16 h2v __attribute__((ext_vector_type(2)));
typedef __fp16 fp16x2 __attribute__((ext_vector_type(2)));
typedef unsigned short u16;

typedef __attribute__((address_space(3))) unsigned int lds_u32;
typedef const __attribute__((address_space(1))) unsigned int glb_u32;

DEVI float bf2f(short s) {
  union { unsigned u; float f; } cv;
  cv.u = ((unsigned)(u16)s) << 16;
  return cv.f;
}
DEVI short f2bf(float f) {
  union { float f; unsigned u; } cv; cv.f = f;
  unsigned u = cv.u;
  return (short)((u + 0x7FFFu + ((u >> 16) & 1u)) >> 16);
}
DEVI unsigned cvtpk(float lo, float hi) {  // packed bf16 [hi|lo], RNE (proven R14)
  unsigned r;
  asm("v_cvt_pk_bf16_f32 %0, %1, %2" : "=v"(r) : "v"(lo), "v"(hi));
  return r;
}
DEVI unsigned pkh(float a, float b) {      // packed f16 [b|a], RTZ
  union { fp16x2 h; unsigned u; } cv;
  cv.h = __builtin_amdgcn_cvt_pkrtz(a, b);
  return cv.u;
}
DEVI float fdot2u(unsigned a, unsigned b, float c) {  // f16 dot2, f32 accum (builtin)
  union { unsigned u; h2v h; } ca, cb; ca.u = a; cb.u = b;
  return __builtin_amdgcn_fdot2(ca.h, cb.h, c, false);
}
DEVI float h2lo(unsigned u) { union { unsigned u; h2v h; } c; c.u = u; return (float)c.h.x; }
DEVI float h2hi(unsigned u) { union { unsigned u; h2v h; } c; c.u = u; return (float)c.h.y; }
DEVI void gld16(const void* g, void* l) {
  __builtin_amdgcn_global_load_lds((glb_u32*)g, (lds_u32*)l, 16, 0, 0);
}

// ---------------- prep: transpose + cast weights to bf16 ----------------
__global__ void prep_weights(const float* __restrict__ Wq, const float* __restrict__ Wk,
                             const float* __restrict__ Wv, const float* __restrict__ Wout,
                             short* __restrict__ WcT, short* __restrict__ WoT) {
  int n = blockIdx.x;
  int k = threadIdx.x;
  float v;
  if (n < 256)      v = Wq[k * 256 + n];
  else if (n < 512) v = Wk[k * 256 + (n - 256)];
  else              v = Wv[k * 256 + (n - 512)];
  WcT[n * 256 + k] = f2bf(v);
  if (n < 256) WoT[n * 256 + k] = f2bf(Wout[k * 256 + n]);
}

// ---------------- x -> bf16 cast ----------------
__global__ void x_cast(const float* __restrict__ x, short* __restrict__ xb) {
  for (size_t gidx = (size_t)blockIdx.x * 256 + threadIdx.x; gidx < 4194304;
       gidx += (size_t)4096 * 256) {
    const float4* src = reinterpret_cast<const float4*>(x + gidx * 8);
    float4 a = src[0], c = src[1];
    v8s pk;
    pk[0] = f2bf(a.x); pk[1] = f2bf(a.y); pk[2] = f2bf(a.z); pk[3] = f2bf(a.w);
    pk[4] = f2bf(c.x); pk[5] = f2bf(c.y); pk[6] = f2bf(c.z); pk[7] = f2bf(c.w);
    *reinterpret_cast<v8s*>(xb + gidx * 8) = pk;
  }
}

// ---------------- QKV projection: 256x256 tile, swapped-operand MFMA, wide stores ----------------
// Q/K emitted as f16 (attn consumes via fdot2); V as bf16.
__launch_bounds__(512, 2)
__global__ void proj_gemm(const short* __restrict__ xb, const short* __restrict__ WcT,
                          const float* __restrict__ pos_emb,
                          short* __restrict__ Qb, short* __restrict__ Kb,
                          short* __restrict__ Vb) {
  __shared__ short As[2][256 * 64];
  __shared__ short Bs[2][256 * 64];
  const int t = threadIdx.x;
  const int bi = blockIdx.x;
  const int xcd = bi & 7;
  const int j = bi >> 3;               // 0..191
  const int mtl = j / 3, nt = j % 3;
  const int mt = xcd * 64 + mtl;       // 0..511, bijective
  const int m0 = mt * 256, n0 = nt * 256;
  const int wave = t >> 6, lane = t & 63;
  const int wm = (wave >> 2) * 128, wn = (wave & 3) * 64;
  const int lr = lane & 15, g = lane >> 4;

  const int ro = lane >> 3;
  const int colb = ((lane & 7) * 16) ^ (ro << 4);
  const char* aSrc0 = reinterpret_cast<const char*>(xb + (size_t)(m0 + ro) * 256) + colb;
  const char* bSrc0 = reinterpret_cast<const char*>(WcT + (size_t)(n0 + ro) * 256) + colb;

  auto stage = [&](int buf, int ks) {
#pragma unroll
    for (int c = 0; c < 4; ++c) {
      int cc = wave * 4 + c;
      gld16(aSrc0 + (size_t)cc * 8 * 512 + ks * 128, (char*)As[buf] + cc * 1024);
      gld16(bSrc0 + (size_t)cc * 8 * 512 + ks * 128, (char*)Bs[buf] + cc * 1024);
    }
  };

  v4f acc[8][4];
#pragma unroll
  for (int i = 0; i < 8; ++i)
#pragma unroll
    for (int jj = 0; jj < 4; ++jj) acc[i][jj] = (v4f){0.f, 0.f, 0.f, 0.f};

  stage(0, 0);
  __syncthreads();

#pragma unroll 1
  for (int s = 0; s < 4; ++s) {
    const int buf = s & 1;
    if (s < 3) stage(buf ^ 1, s + 1);

    const char* aB = (const char*)As[buf];
    const char* bB = (const char*)Bs[buf];
#pragma unroll
    for (int kk = 0; kk < 2; ++kk) {
      v8s bfr[4];
#pragma unroll
      for (int jj = 0; jj < 4; ++jj) {
        int rn = wn + jj * 16 + lr;
        bfr[jj] = *reinterpret_cast<const v8s*>(
            bB + ((rn * 128 + kk * 64 + g * 16) ^ ((rn & 7) << 4)));
      }
#pragma unroll
      for (int i = 0; i < 8; ++i) {
        int row = wm + i * 16 + lr;
        v8s af = *reinterpret_cast<const v8s*>(
            aB + ((row * 128 + kk * 64 + g * 16) ^ ((row & 7) << 4)));
#pragma unroll
        for (int jj = 0; jj < 4; ++jj)
          acc[i][jj] = __builtin_amdgcn_mfma_f32_16x16x32_bf16(bfr[jj], af, acc[i][jj], 0, 0, 0);
      }
    }
    __syncthreads();
  }

  short* dst = (nt == 0) ? Qb : (nt == 1) ? Kb : Vb;
#pragma unroll
  for (int i = 0; i < 8; ++i) {
    int p = m0 + wm + i * 16 + lr;
    int qi = 0;
    if (nt == 0) {
      int yy = (p >> 7) & 127, xx = p & 127;
      qi = (yy - min(max(yy, 2), 125) + 2) * 5 + (xx - min(max(xx, 2), 125) + 2);
    }
#pragma unroll
    for (int jj = 0; jj < 4; ++jj) {
      int nb = wn + jj * 16 + g * 4;
      v4f a = acc[i][jj];
      if (nt == 0) {
        float4 pe4 = *reinterpret_cast<const float4*>(pos_emb + qi * 256 + nb);
        a[0] += pe4.x; a[1] += pe4.y; a[2] += pe4.z; a[3] += pe4.w;
      }
      uint2 pk;
      if (nt == 2) {             // V: bf16 (attn's shift-unpack path)
        pk.x = cvtpk(a[0], a[1]);
        pk.y = cvtpk(a[2], a[3]);
      } else {                   // Q, K: f16 (attn's fdot2 path)
        pk.x = pkh(a[0], a[1]);
        pk.y = pkh(a[2], a[3]);
      }
      *reinterpret_cast<uint2*>(dst + (size_t)p * 256 + nb) = pk;
    }
  }
}

// ---------------- attention: split-F, f16 QK via fdot2, pe path = R14 verbatim ----------------
__launch_bounds__(256, 4)
__global__ void attn_kernel(const short* __restrict__ Qb, const short* __restrict__ Kb,
                            const short* __restrict__ Vb, const float* __restrict__ pos_emb,
                            short* __restrict__ ACC) {
  __shared__ float pe[25 * 256];
  for (int i = threadIdx.x; i < 1600; i += 256) {
    float4 vv = reinterpret_cast<const float4*>(pos_emb)[i];
    int w = i * 4;
    int f = w & 255;
    int dst = (w & ~255) + (f ^ ((f >> 5) << 2));
    *reinterpret_cast<float4*>(pe + dst) = vv;
  }

  const int t = threadIdx.x;
  const int half = t & 1, h = (t >> 1) & 7, pl = t >> 4;
  const int id = blockIdx.x;
  const int b = id & 7;
  const int local = id >> 3;
  const int bx = local & 31, by = local >> 5;
  const int xx = bx * 4 + (pl & 3);
  const int yy = by * 4 + (pl >> 2);
  const int yc = min(max(yy, 2), 125), xc = min(max(xx, 2), 125);
  const int fo = h * 32 + half * 16;
  const int hx4 = h << 2;
  const size_t pbase = ((size_t)((b * 128 + yy) * 128 + xx)) * 256 + fo;
  const size_t cbase = ((size_t)((b * 128 + yc) * 128 + xc)) * 256 + fo;
  const float SCALE2 = 0.17677669529663689f * 1.4426950408889634f;  // rsqrt(32)*log2(e)

  // Q slice: packed f16 (for fdot2) + unpacked f32 (for pe-dot path)
  uint4 qA = *reinterpret_cast<const uint4*>(Qb + pbase);
  uint4 qB = *reinterpret_cast<const uint4*>(Qb + pbase + 8);
  float q[16];
  q[0] = h2lo(qA.x); q[1] = h2hi(qA.x); q[2] = h2lo(qA.y); q[3] = h2hi(qA.y);
  q[4] = h2lo(qA.z); q[5] = h2hi(qA.z); q[6] = h2lo(qA.w); q[7] = h2hi(qA.w);
  q[8] = h2lo(qB.x); q[9] = h2hi(qB.x); q[10] = h2lo(qB.y); q[11] = h2hi(qB.y);
  q[12] = h2lo(qB.z); q[13] = h2hi(qB.z); q[14] = h2lo(qB.w); q[15] = h2hi(qB.w);
  __syncthreads();

  float l = 0.f;
  float oa[16];
#pragma unroll
  for (int f = 0; f < 16; ++f) oa[f] = 0.f;

  const short* kb = Kb + cbase;
  const short* vb = Vb + cbase;
  const float* pb = pe + h * 32;
  const int j0 = (half * 16) ^ hx4;
  const int j1 = (half * 16 + 4) ^ hx4;
  const int j2 = (half * 16 + 8) ^ hx4;
  const int j3 = (half * 16 + 12) ^ hx4;

  uint4 kn0, kn1;
  v8s vn0, vn1;
  {
    const short* kp = kb + (-2 * 128 - 2) * 256;
    const short* vp = vb + (-2 * 128 - 2) * 256;
    kn0 = *reinterpret_cast<const uint4*>(kp);
    kn1 = *reinterpret_cast<const uint4*>(kp + 8);
    vn0 = *reinterpret_cast<const v8s*>(vp);
    vn1 = *reinterpret_cast<const v8s*>(vp + 8);
  }

#pragma unroll 1
  for (int dy = -2; dy <= 2; ++dy) {
    const float* prow = pb + ((dy + 2) * 5) * 256;
#pragma unroll 1
    for (int dx = -2; dx <= 2; ++dx) {
      uint4 k0 = kn0, k1 = kn1;
      v8s v0 = vn0, v1 = vn1;
      int ndx = dx + 1, ndy = dy;
      if (ndx > 2) { ndx = -2; ndy = dy + 1; }
      if (ndy <= 2) {
        const short* kp2 = kb + (ndy * 128 + ndx) * 256;
        const short* vp2 = vb + (ndy * 128 + ndx) * 256;
        kn0 = *reinterpret_cast<const uint4*>(kp2);
        kn1 = *reinterpret_cast<const uint4*>(kp2 + 8);
        vn0 = *reinterpret_cast<const v8s*>(vp2);
        vn1 = *reinterpret_cast<const v8s*>(vp2 + 8);
      }
      const float* pp = prow + (dx + 2) * 256;
      float4 p0 = *reinterpret_cast<const float4*>(pp + j0);
      float4 p1 = *reinterpret_cast<const float4*>(pp + j1);
      float4 p2 = *reinterpret_cast<const float4*>(pp + j2);
      float4 p3 = *reinterpret_cast<const float4*>(pp + j3);

      // QK dot: 8 packed f16 dot2 (f32 accumulate)
      float d0 = 0.f, d1 = 0.f, d2 = 0.f, d3 = 0.f;
      d0 = fdot2u(qA.x, k0.x, d0); d1 = fdot2u(qA.y, k0.y, d1);
      d2 = fdot2u(qA.z, k0.z, d2); d3 = fdot2u(qA.w, k0.w, d3);
      d0 = fdot2u(qB.x, k1.x, d0); d1 = fdot2u(qB.y, k1.y, d1);
      d2 = fdot2u(qB.z, k1.z, d2); d3 = fdot2u(qB.w, k1.w, d3);

      // pe contribution: f32 fma path (R14 verbatim)
      d0 = fmaf(q[0], p0.x, d0); d0 = fmaf(q[1], p0.y, d0);
      d0 = fmaf(q[2], p0.z, d0); d0 = fmaf(q[3], p0.w, d0);
      d1 = fmaf(q[4], p1.x, d1); d1 = fmaf(q[5], p1.y, d1);
      d1 = fmaf(q[6], p1.z, d1); d1 = fmaf(q[7], p1.w, d1);
      d2 = fmaf(q[8], p2.x, d2); d2 = fmaf(q[9], p2.y, d2);
      d2 = fmaf(q[10], p2.z, d2); d2 = fmaf(q[11], p2.w, d2);
      d3 = fmaf(q[12], p3.x, d3); d3 = fmaf(q[13], p3.y, d3);
      d3 = fmaf(q[14], p3.z, d3); d3 = fmaf(q[15], p3.w, d3);

      float part = ((d0 + d1) + (d2 + d3)) * SCALE2;
      float full = part + __shfl_xor(part, 1);
      float w = exp2f(full);
      l += w;
#pragma unroll
      for (int e = 0; e < 8; ++e) oa[e] = fmaf(w, bf2f(v0[e]), oa[e]);
#pragma unroll
      for (int e = 0; e < 8; ++e) oa[8 + e] = fmaf(w, bf2f(v1[e]), oa[8 + e]);
    }
  }

  float inv = 1.f / l;
  uint4 o0, o1;
  o0.x = cvtpk(oa[0] * inv, oa[1] * inv);
  o0.y = cvtpk(oa[2] * inv, oa[3] * inv);
  o0.z = cvtpk(oa[4] * inv, oa[5] * inv);
  o0.w = cvtpk(oa[6] * inv, oa[7] * inv);
  o1.x = cvtpk(oa[8] * inv, oa[9] * inv);
  o1.y = cvtpk(oa[10] * inv, oa[11] * inv);
  o1.z = cvtpk(oa[12] * inv, oa[13] * inv);
  o1.w = cvtpk(oa[14] * inv, oa[15] * inv);
  *reinterpret_cast<uint4*>(ACC + pbase) = o0;
  *reinterpret_cast<uint4*>(ACC + pbase + 8) = o1;
}

// ---------------- output projection: 256x256 tile, swapped operands, float4 stores ----------------
__launch_bounds__(512, 2)
__global__ void out_gemm(const short* __restrict__ A, const short* __restrict__ WoT,
                         float* __restrict__ out) {
  __shared__ short As[2][256 * 64];
  __shared__ short Bs[2][256 * 64];
  const int t = threadIdx.x;
  const int bi = blockIdx.x;
  const int xcd = bi & 7;
  const int mt = xcd * 64 + (bi >> 3);
  const int m0 = mt * 256;
  const int wave = t >> 6, lane = t & 63;
  const int wm = (wave >> 2) * 128, wn = (wave & 3) * 64;
  const int lr = lane & 15, g = lane >> 4;

  const int ro = lane >> 3;
  const int colb = ((lane & 7) * 16) ^ (ro << 4);
  const char* aSrc0 = reinterpret_cast<const char*>(A + (size_t)(m0 + ro) * 256) + colb;
  const char* bSrc0 = reinterpret_cast<const char*>(WoT + (size_t)ro * 256) + colb;

  auto stage = [&](int buf, int ks) {
#pragma unroll
    for (int c = 0; c < 4; ++c) {
      int cc = wave * 4 + c;
      gld16(aSrc0 + (size_t)cc * 8 * 512 + ks * 128, (char*)As[buf] + cc * 1024);
      gld16(bSrc0 + (size_t)cc * 8 * 512 + ks * 128, (char*)Bs[buf] + cc * 1024);
    }
  };

  v4f acc[8][4];
#pragma unroll
  for (int i = 0; i < 8; ++i)
#pragma unroll
    for (int jj = 0; jj < 4; ++jj) acc[i][jj] = (v4f){0.f, 0.f, 0.f, 0.f};

  stage(0, 0);
  __syncthreads();

#pragma unroll 1
  for (int s = 0; s < 4; ++s) {
    const int buf = s & 1;
    if (s < 3) stage(buf ^ 1, s + 1);

    const char* aB = (const char*)As[buf];
    const char* bB = (const char*)Bs[buf];
#pragma unroll
    for (int kk = 0; kk < 2; ++kk) {
      v8s bfr[4];
#pragma unroll
      for (int jj = 0; jj < 4; ++jj) {
        int rn = wn + jj * 16 + lr;
        bfr[jj] = *reinterpret_cast<const v8s*>(
            bB + ((rn * 128 + kk * 64 + g * 16) ^ ((rn & 7) << 4)));
      }
#pragma unroll
      for (int i = 0; i < 8; ++i) {
        int row = wm + i * 16 + lr;
        v8s af = *reinterpret_cast<const v8s*>(
            aB + ((row * 128 + kk * 64 + g * 16) ^ ((row & 7) << 4)));
#pragma unroll
        for (int jj = 0; jj < 4; ++jj)
          acc[i][jj] = __builtin_amdgcn_mfma_f32_16x16x32_bf16(bfr[jj], af, acc[i][jj], 0, 0, 0);
      }
    }
    __syncthreads();
  }

#pragma unroll
  for (int i = 0; i < 8; ++i) {
    int p = m0 + wm + i * 16 + lr;
#pragma unroll
    for (int jj = 0; jj < 4; ++jj) {
      int nb = wn + jj * 16 + g * 4;
      float4 o;
      o.x = acc[i][jj][0]; o.y = acc[i][jj][1];
      o.z = acc[i][jj][2]; o.w = acc[i][jj][3];
      *reinterpret_cast<float4*>(out + (size_t)p * 256 + nb) = o;
    }
  }
}

extern "C" void kernel_launch(void* const* d_in, const int* in_sizes, int n_in,
                              void* d_out, int out_size, void* d_ws, size_t ws_size,
                              hipStream_t stream) {
  const float* x       = (const float*)d_in[0];
  const float* Wq      = (const float*)d_in[1];
  const float* Wk      = (const float*)d_in[2];
  const float* Wv      = (const float*)d_in[3];
  const float* Wout    = (const float*)d_in[4];
  const float* pos_emb = (const float*)d_in[5];
  float* out = (float*)d_out;

  char* ws = (char*)d_ws;
  short* WcT  = (short*)ws;                       // 768*256*2   = 393216 B
  short* WoT  = (short*)(ws + 393216);            // 256*256*2   = 131072 B
  short* Qb   = (short*)(ws + 524288);            // 131072*256*2 each
  short* Kb   = Qb + (size_t)131072 * 256;
  short* Vb   = Kb + (size_t)131072 * 256;
  short* ACCb = Vb + (size_t)131072 * 256;
  short* xb   = ACCb;   // alias: xb used only before attn writes ACCb

  prep_weights<<<768, 256, 0, stream>>>(Wq, Wk, Wv, Wout, WcT, WoT);
  x_cast<<<4096, 256, 0, stream>>>(x, xb);
  proj_gemm<<<1536, 512, 0, stream>>>(xb, WcT, pos_emb, Qb, Kb, Vb);
  attn_kernel<<<8192, 256, 0, stream>>>(Qb, Kb, Vb, pos_emb, ACCb);
  out_gemm<<<512, 512, 0, stream>>>(ACCb, WoT, out);
}